// Round 3
// baseline (1205.086 us; speedup 1.0000x reference)
//
#include <hip/hip_runtime.h>

#define LOG2E 1.44269504088896340736f

typedef _Float16 f16;
typedef __attribute__((ext_vector_type(4))) _Float16 f16x4;
typedef __attribute__((ext_vector_type(8))) _Float16 f16x8;
typedef __attribute__((ext_vector_type(4))) float f32x4;
typedef __attribute__((ext_vector_type(8))) unsigned short us8;

#define BB 32
#define SSX 2048
#define SSY 2048
#define DD 160
#define M_TOTAL (BB*SSX)   // 65536

#define PRS 168    // proj LDS row stride (f16): 160 + 8, 16B-aligned rows
#define VTRS 136   // proj V^T store buffer stride (128 + 8)
#define RS 168     // flash K/Q LDS stride
#define P_RS 72    // flash P LDS stride (64 + 8)

__device__ __forceinline__ f32x4 mfma16(f16x8 a, f16x8 b, f32x4 c) {
  return __builtin_amdgcn_mfma_f32_16x16x32_f16(a, b, c, 0, 0, 0);
}

// ---- Projection: Q = x Wq^T + bq ; K,V from y (V stored transposed). ----
// Precision: x -> f16 once; W split into hi+lo f16 (2 MFMA chains).
__global__ __launch_bounds__(256) void proj_kernel(
    const float* __restrict__ x, const float* __restrict__ y,
    const float* __restrict__ Wq, const float* __restrict__ bq,
    const float* __restrict__ Wk, const float* __restrict__ bk,
    const float* __restrict__ Wv, const float* __restrict__ bv,
    f16* __restrict__ Qw, f16* __restrict__ Kw, f16* __restrict__ Vtw)
{
  __shared__ __align__(16) f16 buf[160*PRS];   // 53760 B
  const int t = threadIdx.x;
  const int wave = t >> 6;
  const int lane = t & 63;
  const int quad = lane >> 4;
  const int l16  = lane & 15;
  const int bid  = blockIdx.x;
  const bool qpath = bid < 512;
  const int tile = qpath ? bid : bid - 512;
  const int row0 = tile * 128;
  const float* src = qpath ? x : y;

  // stage 128x160 input tile fp32 -> f16 (float4 loads, 8B LDS stores)
  for (int i = 0; i < 20; ++i) {
    int idx = t + i*256;           // 5120 float4 total
    int r = idx / 40, c4 = idx % 40;
    float4 v = *(const float4*)&src[(size_t)(row0 + r)*DD + c4*4];
    f16x4 h = { (f16)v.x, (f16)v.y, (f16)v.z, (f16)v.w };
    *(f16x4*)&buf[r*PRS + c4*4] = h;
  }
  __syncthreads();
  f16x8 afr[2][5];
  #pragma unroll
  for (int u = 0; u < 2; ++u)
    #pragma unroll
    for (int ks = 0; ks < 5; ++ks)
      afr[u][ks] = *(const f16x8*)&buf[(wave*32 + u*16 + l16)*PRS + ks*32 + quad*8];
  __syncthreads();

  f32x4 acc[2][10];

  auto stage_W = [&](const float* W, bool lo) {
    for (int i = 0; i < 25; ++i) {
      int idx = t + i*256;         // 6400 float4 = 160x160
      int r = idx / 40, c4 = idx % 40;
      float4 v = *(const float4*)&W[r*160 + c4*4];
      f16x4 h;
      if (!lo) h = (f16x4){ (f16)v.x, (f16)v.y, (f16)v.z, (f16)v.w };
      else h = (f16x4){ (f16)(v.x-(float)(f16)v.x), (f16)(v.y-(float)(f16)v.y),
                        (f16)(v.z-(float)(f16)v.z), (f16)(v.w-(float)(f16)v.w) };
      *(f16x4*)&buf[r*PRS + c4*4] = h;
    }
  };
  auto mfma_pass = [&](bool init, const float* bias) {
    #pragma unroll
    for (int nt = 0; nt < 10; ++nt) {
      if (init) {
        float bs = bias[nt*16 + l16];
        acc[0][nt] = (f32x4){bs,bs,bs,bs};
        acc[1][nt] = (f32x4){bs,bs,bs,bs};
      }
      #pragma unroll
      for (int ks = 0; ks < 5; ++ks) {
        f16x8 bfr = *(const f16x8*)&buf[(nt*16 + l16)*PRS + ks*32 + quad*8];
        acc[0][nt] = mfma16(afr[0][ks], bfr, acc[0][nt]);
        acc[1][nt] = mfma16(afr[1][ks], bfr, acc[1][nt]);
      }
    }
  };
  auto do_proj = [&](const float* W, const float* bias) {
    stage_W(W, false); __syncthreads(); mfma_pass(true, bias);  __syncthreads();
    stage_W(W, true);  __syncthreads(); mfma_pass(false, bias); __syncthreads();
  };
  auto store_rowmajor = [&](f16* dst) {
    #pragma unroll
    for (int u = 0; u < 2; ++u)
      #pragma unroll
      for (int nt = 0; nt < 10; ++nt)
        #pragma unroll
        for (int r = 0; r < 4; ++r)
          buf[(wave*32 + u*16 + quad*4 + r)*PRS + nt*16 + l16] = (f16)acc[u][nt][r];
    __syncthreads();
    for (int i = 0; i < 10; ++i) {
      int idx = t + i*256;          // 2560 us8 = 128x160 f16
      int r = idx / 20, g = idx % 20;
      *(us8*)&dst[(size_t)(row0 + r)*DD + g*8] = *(const us8*)&buf[r*PRS + g*8];
    }
    __syncthreads();
  };

  if (qpath) {
    do_proj(Wq, bq);
    store_rowmajor(Qw);
  } else {
    do_proj(Wk, bk);
    store_rowmajor(Kw);
    do_proj(Wv, bv);
    // V^T: acc -> buf[d][y_local] (stride VTRS) -> coalesced us8 stores
    #pragma unroll
    for (int u = 0; u < 2; ++u)
      #pragma unroll
      for (int nt = 0; nt < 10; ++nt)
        #pragma unroll
        for (int r = 0; r < 4; ++r)
          buf[(nt*16 + l16)*VTRS + wave*32 + u*16 + quad*4 + r] = (f16)acc[u][nt][r];
    __syncthreads();
    const int b  = row0 / SSY;
    const int y0 = row0 % SSY;
    for (int i = 0; i < 10; ++i) {
      int idx = t + i*256;          // 2560 us8 = 160 d x 128 y
      int d = idx / 16, yg = idx % 16;
      *(us8*)&Vtw[((size_t)b*DD + d)*SSY + y0 + yg*8] = *(const us8*)&buf[d*VTRS + yg*8];
    }
  }
}

// ---------------- Flash attention + residual ----------------
__global__ __launch_bounds__(256, 3) void flash_kernel(
    const f16* __restrict__ Qw, const f16* __restrict__ Kw, const f16* __restrict__ Vtw,
    const float* __restrict__ x, float* __restrict__ out)
{
  __shared__ __align__(16) f16 K_lds[64*RS];     // 21504 B (also Q staging)
  __shared__ __align__(16) f16 Vt_lds[160*64];   // 20480 B, XOR-swizzled granules
  __shared__ __align__(16) f16 P_lds[4*16*P_RS]; //  9216 B -> total 51200 B, 3 blocks/CU
  const int t = threadIdx.x;
  const int wave = t >> 6;
  const int lane = t & 63;
  const int quad = lane >> 4;
  const int l16  = lane & 15;
  const int bid  = blockIdx.x;
  const int b    = bid >> 5;
  const int x0   = (bid & 31) * 64;

  // stage Q tile (reuses K_lds), hoist A-frags
  {
    const f16* qsrc = Qw + ((size_t)b*SSX + x0)*DD;
    for (int i = 0; i < 5; ++i) {
      int idx = t + i*256;
      int r = idx / 20, c = idx % 20;
      *(us8*)&K_lds[r*RS + c*8] = *(const us8*)&qsrc[(size_t)r*DD + c*8];
    }
  }
  __syncthreads();
  f16x8 qfr[5];
  #pragma unroll
  for (int ks = 0; ks < 5; ++ks)
    qfr[ks] = *(const f16x8*)&K_lds[(wave*16 + l16)*RS + ks*32 + quad*8];

  f32x4 acc[10];
  #pragma unroll
  for (int i = 0; i < 10; ++i) acc[i] = (f32x4){0.f,0.f,0.f,0.f};
  float m_i[4], l_i[4];
  #pragma unroll
  for (int r = 0; r < 4; ++r) { m_i[r] = -1e30f; l_i[r] = 0.f; }

  f16* Pw = &P_lds[wave*16*P_RS];

  for (int yc = 0; yc < SSY/64; ++yc) {
    const int ybase = yc*64;
    __syncthreads();  // previous iteration's reads done before restaging
    {
      const f16* ksrc = Kw + ((size_t)b*SSY + ybase)*DD;
      for (int i = 0; i < 5; ++i) {
        int idx = t + i*256;
        int r = idx / 20, c = idx % 20;
        *(us8*)&K_lds[r*RS + c*8] = *(const us8*)&ksrc[(size_t)r*DD + c*8];
      }
      const f16* vsrc = Vtw + (size_t)b*DD*SSY + ybase;
      for (int i = 0; i < 5; ++i) {
        int idx = t + i*256;        // 1280 us8 = 160 d x 8 granules
        int d = idx >> 3, g = idx & 7;
        *(us8*)&Vt_lds[d*64 + ((g ^ (d & 7)) << 3)] = *(const us8*)&vsrc[(size_t)d*SSY + g*8];
      }
    }
    __syncthreads();

    // S = Q K^T  (16 q-rows x 64 y-cols per wave)
    f32x4 S[4];
    #pragma unroll
    for (int nt = 0; nt < 4; ++nt) {
      S[nt] = (f32x4){0.f,0.f,0.f,0.f};
      #pragma unroll
      for (int ks = 0; ks < 5; ++ks) {
        f16x8 kfr = *(const f16x8*)&K_lds[(nt*16 + l16)*RS + ks*32 + quad*8];
        S[nt] = mfma16(qfr[ks], kfr, S[nt]);
      }
    }

    // online softmax; rows m = quad*4+r, cols across l16 and nt
    float mn4[4];
    bool changed = false;
    #pragma unroll
    for (int r = 0; r < 4; ++r) {
      float mx = fmaxf(fmaxf(S[0][r], S[1][r]), fmaxf(S[2][r], S[3][r]));
      #pragma unroll
      for (int off = 1; off < 16; off <<= 1) mx = fmaxf(mx, __shfl_xor(mx, off));
      mn4[r] = fmaxf(m_i[r], mx);
      changed = changed || (mn4[r] > m_i[r]);
    }
    if (__any(changed)) {   // rescale only when some row's max moved (rare after warmup)
      float al[4];
      #pragma unroll
      for (int r = 0; r < 4; ++r) {
        al[r] = exp2f((m_i[r] - mn4[r])*LOG2E);
        m_i[r] = mn4[r];
        l_i[r] *= al[r];
      }
      f32x4 av = {al[0], al[1], al[2], al[3]};
      #pragma unroll
      for (int i = 0; i < 10; ++i) acc[i] *= av;
    }
    #pragma unroll
    for (int r = 0; r < 4; ++r) {
      float rs = 0.f;
      #pragma unroll
      for (int nt = 0; nt < 4; ++nt) {
        float p = exp2f((S[nt][r] - m_i[r])*LOG2E);
        S[nt][r] = p;
        rs += p;
      }
      #pragma unroll
      for (int off = 1; off < 16; off <<= 1) rs += __shfl_xor(rs, off);
      l_i[r] += rs;
    }

    // P (C/D layout) -> LDS -> A-operand layout (per-wave region)
    #pragma unroll
    for (int nt = 0; nt < 4; ++nt)
      #pragma unroll
      for (int r = 0; r < 4; ++r)
        Pw[(quad*4 + r)*P_RS + nt*16 + l16] = (f16)S[nt][r];

    #pragma unroll
    for (int k2 = 0; k2 < 2; ++k2) {
      f16x8 pfr = *(const f16x8*)&Pw[l16*P_RS + k2*32 + quad*8];
      #pragma unroll
      for (int dt = 0; dt < 10; ++dt) {
        int row = dt*16 + l16;
        f16x8 vfr = *(const f16x8*)&Vt_lds[row*64 + (((k2*4 + quad) ^ (l16 & 7)) << 3)];
        acc[dt] = mfma16(pfr, vfr, acc[dt]);
      }
    }
  }

  // epilogue: out = acc/l + x
  const size_t base = ((size_t)b*SSX + x0 + wave*16)*DD;
  float rl[4];
  #pragma unroll
  for (int r = 0; r < 4; ++r) rl[r] = 1.f/l_i[r];
  #pragma unroll
  for (int dt = 0; dt < 10; ++dt)
    #pragma unroll
    for (int r = 0; r < 4; ++r) {
      size_t o = base + (size_t)(quad*4 + r)*DD + dt*16 + l16;
      out[o] = acc[dt][r]*rl[r] + x[o];
    }
}

extern "C" void kernel_launch(void* const* d_in, const int* in_sizes, int n_in,
                              void* d_out, int out_size, void* d_ws, size_t ws_size,
                              hipStream_t stream) {
  const float* x  = (const float*)d_in[0];
  const float* y  = (const float*)d_in[1];
  const float* Wq = (const float*)d_in[2];
  const float* bq = (const float*)d_in[3];
  const float* Wk = (const float*)d_in[4];
  const float* bk = (const float*)d_in[5];
  const float* Wv = (const float*)d_in[6];
  const float* bv = (const float*)d_in[7];

  f16* Qw  = (f16*)d_ws;
  f16* Kw  = Qw + (size_t)M_TOTAL*DD;
  f16* Vtw = Kw + (size_t)M_TOTAL*DD;   // 63 MB of workspace total

  proj_kernel<<<1024, 256, 0, stream>>>(x, y, Wq, bq, Wk, bk, Wv, bv, Qw, Kw, Vtw);
  flash_kernel<<<1024, 256, 0, stream>>>(Qw, Kw, Vtw, x, (float*)d_out);
}

// Round 4
// 355.714 us; speedup vs baseline: 3.3878x; 3.3878x over previous
//
#include <hip/hip_runtime.h>

#define LOG2E 1.44269504088896340736f

typedef _Float16 f16;
typedef __attribute__((ext_vector_type(4))) _Float16 f16x4;
typedef __attribute__((ext_vector_type(8))) _Float16 f16x8;
typedef __attribute__((ext_vector_type(4))) float f32x4;
typedef __attribute__((ext_vector_type(8))) unsigned short us8;

#define BB 32
#define SSX 2048
#define SSY 2048
#define DD 160
#define M_TOTAL (BB*SSX)   // 65536

#define PRS 168    // proj LDS row stride (f16): 160 + 8, 16B-aligned rows
#define VTRS 136   // proj V^T store buffer stride (128 + 8)
#define RS 168     // flash K/Q LDS stride
#define P_RS 72    // flash P LDS stride (64 + 8)

__device__ __forceinline__ f32x4 mfma16(f16x8 a, f16x8 b, f32x4 c) {
  return __builtin_amdgcn_mfma_f32_16x16x32_f16(a, b, c, 0, 0, 0);
}

// ---- Projection: Q = x Wq^T + bq ; K,V from y (V stored transposed). ----
// Straight-line macros (NO lambdas: round-3 showed lambda-captured acc arrays
// get address-taken -> scratch spill -> 1.3 GB/dispatch HBM traffic, 962 us).

#define STAGE_W_HI(W) \
  for (int i = 0; i < 25; ++i) { \
    int idx = t + i*256; \
    int r = idx / 40, c4 = idx % 40; \
    float4 v = *(const float4*)&(W)[r*160 + c4*4]; \
    f16x4 h = { (f16)v.x, (f16)v.y, (f16)v.z, (f16)v.w }; \
    *(f16x4*)&buf[r*PRS + c4*4] = h; \
  }

#define STAGE_W_LO(W) \
  for (int i = 0; i < 25; ++i) { \
    int idx = t + i*256; \
    int r = idx / 40, c4 = idx % 40; \
    float4 v = *(const float4*)&(W)[r*160 + c4*4]; \
    f16x4 h = { (f16)(v.x-(float)(f16)v.x), (f16)(v.y-(float)(f16)v.y), \
                (f16)(v.z-(float)(f16)v.z), (f16)(v.w-(float)(f16)v.w) }; \
    *(f16x4*)&buf[r*PRS + c4*4] = h; \
  }

#define MFMA_PASS(INIT, bias) \
  _Pragma("unroll") \
  for (int nt = 0; nt < 10; ++nt) { \
    if (INIT) { \
      float bs = (bias)[nt*16 + l16]; \
      acc0[nt] = (f32x4){bs,bs,bs,bs}; \
      acc1[nt] = (f32x4){bs,bs,bs,bs}; \
    } \
    _Pragma("unroll") \
    for (int ks = 0; ks < 5; ++ks) { \
      f16x8 bfr = *(const f16x8*)&buf[(nt*16 + l16)*PRS + ks*32 + quad*8]; \
      acc0[nt] = mfma16(afr0[ks], bfr, acc0[nt]); \
      acc1[nt] = mfma16(afr1[ks], bfr, acc1[nt]); \
    } \
  }

#define DO_PROJ(W, bias) \
  STAGE_W_HI(W); __syncthreads(); MFMA_PASS(true, bias); __syncthreads(); \
  STAGE_W_LO(W); __syncthreads(); MFMA_PASS(false, bias); __syncthreads();

#define STORE_ROWMAJOR(dst) \
  _Pragma("unroll") \
  for (int u = 0; u < 2; ++u) \
    _Pragma("unroll") \
    for (int nt = 0; nt < 10; ++nt) \
      _Pragma("unroll") \
      for (int r = 0; r < 4; ++r) \
        buf[(wave*32 + u*16 + quad*4 + r)*PRS + nt*16 + l16] = \
            (f16)((u ? acc1 : acc0)[nt][r]); \
  __syncthreads(); \
  for (int i = 0; i < 10; ++i) { \
    int idx = t + i*256; \
    int r = idx / 20, g = idx % 20; \
    *(us8*)&(dst)[(size_t)(row0 + r)*DD + g*8] = *(const us8*)&buf[r*PRS + g*8]; \
  } \
  __syncthreads();

__global__ __launch_bounds__(256, 2) void proj_kernel(
    const float* __restrict__ x, const float* __restrict__ y,
    const float* __restrict__ Wq, const float* __restrict__ bq,
    const float* __restrict__ Wk, const float* __restrict__ bk,
    const float* __restrict__ Wv, const float* __restrict__ bv,
    f16* __restrict__ Qw, f16* __restrict__ Kw, f16* __restrict__ Vtw)
{
  __shared__ __align__(16) f16 buf[160*PRS];   // 53760 B
  const int t = threadIdx.x;
  const int wave = t >> 6;
  const int lane = t & 63;
  const int quad = lane >> 4;
  const int l16  = lane & 15;
  const int bid  = blockIdx.x;
  const bool qpath = bid < 512;
  const int tile = qpath ? bid : bid - 512;
  const int row0 = tile * 128;
  const float* src = qpath ? x : y;

  // stage 128x160 input tile fp32 -> f16 (float4 loads, 8B LDS stores)
  for (int i = 0; i < 20; ++i) {
    int idx = t + i*256;           // 5120 float4 total
    int r = idx / 40, c4 = idx % 40;
    float4 v = *(const float4*)&src[(size_t)(row0 + r)*DD + c4*4];
    f16x4 h = { (f16)v.x, (f16)v.y, (f16)v.z, (f16)v.w };
    *(f16x4*)&buf[r*PRS + c4*4] = h;
  }
  __syncthreads();
  f16x8 afr0[5], afr1[5];
  #pragma unroll
  for (int ks = 0; ks < 5; ++ks) {
    afr0[ks] = *(const f16x8*)&buf[(wave*32 + l16)*PRS + ks*32 + quad*8];
    afr1[ks] = *(const f16x8*)&buf[(wave*32 + 16 + l16)*PRS + ks*32 + quad*8];
  }
  __syncthreads();

  f32x4 acc0[10], acc1[10];

  if (qpath) {
    DO_PROJ(Wq, bq);
    STORE_ROWMAJOR(Qw);
  } else {
    DO_PROJ(Wk, bk);
    STORE_ROWMAJOR(Kw);
    DO_PROJ(Wv, bv);
    // V^T: acc -> buf[d][y_local] (stride VTRS) -> coalesced us8 stores
    #pragma unroll
    for (int nt = 0; nt < 10; ++nt)
      #pragma unroll
      for (int r = 0; r < 4; ++r) {
        buf[(nt*16 + l16)*VTRS + wave*32 + quad*4 + r]      = (f16)acc0[nt][r];
        buf[(nt*16 + l16)*VTRS + wave*32 + 16 + quad*4 + r] = (f16)acc1[nt][r];
      }
    __syncthreads();
    const int b  = row0 / SSY;
    const int y0 = row0 % SSY;
    for (int i = 0; i < 10; ++i) {
      int idx = t + i*256;          // 2560 us8 = 160 d x 128 y
      int d = idx / 16, yg = idx % 16;
      *(us8*)&Vtw[((size_t)b*DD + d)*SSY + y0 + yg*8] = *(const us8*)&buf[d*VTRS + yg*8];
    }
  }
}

// ---------------- Flash attention + residual (unchanged from round 3) ----------------
__global__ __launch_bounds__(256, 3) void flash_kernel(
    const f16* __restrict__ Qw, const f16* __restrict__ Kw, const f16* __restrict__ Vtw,
    const float* __restrict__ x, float* __restrict__ out)
{
  __shared__ __align__(16) f16 K_lds[64*RS];     // 21504 B (also Q staging)
  __shared__ __align__(16) f16 Vt_lds[160*64];   // 20480 B, XOR-swizzled granules
  __shared__ __align__(16) f16 P_lds[4*16*P_RS]; //  9216 B -> total 51200 B, 3 blocks/CU
  const int t = threadIdx.x;
  const int wave = t >> 6;
  const int lane = t & 63;
  const int quad = lane >> 4;
  const int l16  = lane & 15;
  const int bid  = blockIdx.x;
  const int b    = bid >> 5;
  const int x0   = (bid & 31) * 64;

  // stage Q tile (reuses K_lds), hoist A-frags
  {
    const f16* qsrc = Qw + ((size_t)b*SSX + x0)*DD;
    for (int i = 0; i < 5; ++i) {
      int idx = t + i*256;
      int r = idx / 20, c = idx % 20;
      *(us8*)&K_lds[r*RS + c*8] = *(const us8*)&qsrc[(size_t)r*DD + c*8];
    }
  }
  __syncthreads();
  f16x8 qfr[5];
  #pragma unroll
  for (int ks = 0; ks < 5; ++ks)
    qfr[ks] = *(const f16x8*)&K_lds[(wave*16 + l16)*RS + ks*32 + quad*8];

  f32x4 acc[10];
  #pragma unroll
  for (int i = 0; i < 10; ++i) acc[i] = (f32x4){0.f,0.f,0.f,0.f};
  float m_i[4], l_i[4];
  #pragma unroll
  for (int r = 0; r < 4; ++r) { m_i[r] = -1e30f; l_i[r] = 0.f; }

  f16* Pw = &P_lds[wave*16*P_RS];

  for (int yc = 0; yc < SSY/64; ++yc) {
    const int ybase = yc*64;
    __syncthreads();  // previous iteration's reads done before restaging
    {
      const f16* ksrc = Kw + ((size_t)b*SSY + ybase)*DD;
      for (int i = 0; i < 5; ++i) {
        int idx = t + i*256;
        int r = idx / 20, c = idx % 20;
        *(us8*)&K_lds[r*RS + c*8] = *(const us8*)&ksrc[(size_t)r*DD + c*8];
      }
      const f16* vsrc = Vtw + (size_t)b*DD*SSY + ybase;
      for (int i = 0; i < 5; ++i) {
        int idx = t + i*256;        // 1280 us8 = 160 d x 8 granules
        int d = idx >> 3, g = idx & 7;
        *(us8*)&Vt_lds[d*64 + ((g ^ (d & 7)) << 3)] = *(const us8*)&vsrc[(size_t)d*SSY + g*8];
      }
    }
    __syncthreads();

    // S = Q K^T  (16 q-rows x 64 y-cols per wave)
    f32x4 S[4];
    #pragma unroll
    for (int nt = 0; nt < 4; ++nt) {
      S[nt] = (f32x4){0.f,0.f,0.f,0.f};
      #pragma unroll
      for (int ks = 0; ks < 5; ++ks) {
        f16x8 kfr = *(const f16x8*)&K_lds[(nt*16 + l16)*RS + ks*32 + quad*8];
        S[nt] = mfma16(qfr[ks], kfr, S[nt]);
      }
    }

    // online softmax; rows m = quad*4+r, cols across l16 and nt
    float mn4[4];
    bool changed = false;
    #pragma unroll
    for (int r = 0; r < 4; ++r) {
      float mx = fmaxf(fmaxf(S[0][r], S[1][r]), fmaxf(S[2][r], S[3][r]));
      #pragma unroll
      for (int off = 1; off < 16; off <<= 1) mx = fmaxf(mx, __shfl_xor(mx, off));
      mn4[r] = fmaxf(m_i[r], mx);
      changed = changed || (mn4[r] > m_i[r]);
    }
    if (__any(changed)) {   // rescale only when some row's max moved
      float al[4];
      #pragma unroll
      for (int r = 0; r < 4; ++r) {
        al[r] = exp2f((m_i[r] - mn4[r])*LOG2E);
        m_i[r] = mn4[r];
        l_i[r] *= al[r];
      }
      f32x4 av = {al[0], al[1], al[2], al[3]};
      #pragma unroll
      for (int i = 0; i < 10; ++i) acc[i] *= av;
    }
    #pragma unroll
    for (int r = 0; r < 4; ++r) {
      float rs = 0.f;
      #pragma unroll
      for (int nt = 0; nt < 4; ++nt) {
        float p = exp2f((S[nt][r] - m_i[r])*LOG2E);
        S[nt][r] = p;
        rs += p;
      }
      #pragma unroll
      for (int off = 1; off < 16; off <<= 1) rs += __shfl_xor(rs, off);
      l_i[r] += rs;
    }

    // P (C/D layout) -> LDS -> A-operand layout (per-wave region)
    #pragma unroll
    for (int nt = 0; nt < 4; ++nt)
      #pragma unroll
      for (int r = 0; r < 4; ++r)
        Pw[(quad*4 + r)*P_RS + nt*16 + l16] = (f16)S[nt][r];

    #pragma unroll
    for (int k2 = 0; k2 < 2; ++k2) {
      f16x8 pfr = *(const f16x8*)&Pw[l16*P_RS + k2*32 + quad*8];
      #pragma unroll
      for (int dt = 0; dt < 10; ++dt) {
        int row = dt*16 + l16;
        f16x8 vfr = *(const f16x8*)&Vt_lds[row*64 + (((k2*4 + quad) ^ (l16 & 7)) << 3)];
        acc[dt] = mfma16(pfr, vfr, acc[dt]);
      }
    }
  }

  // epilogue: out = acc/l + x
  const size_t base = ((size_t)b*SSX + x0 + wave*16)*DD;
  float rl[4];
  #pragma unroll
  for (int r = 0; r < 4; ++r) rl[r] = 1.f/l_i[r];
  #pragma unroll
  for (int dt = 0; dt < 10; ++dt)
    #pragma unroll
    for (int r = 0; r < 4; ++r) {
      size_t o = base + (size_t)(quad*4 + r)*DD + dt*16 + l16;
      out[o] = acc[dt][r]*rl[r] + x[o];
    }
}

extern "C" void kernel_launch(void* const* d_in, const int* in_sizes, int n_in,
                              void* d_out, int out_size, void* d_ws, size_t ws_size,
                              hipStream_t stream) {
  const float* x  = (const float*)d_in[0];
  const float* y  = (const float*)d_in[1];
  const float* Wq = (const float*)d_in[2];
  const float* bq = (const float*)d_in[3];
  const float* Wk = (const float*)d_in[4];
  const float* bk = (const float*)d_in[5];
  const float* Wv = (const float*)d_in[6];
  const float* bv = (const float*)d_in[7];

  f16* Qw  = (f16*)d_ws;
  f16* Kw  = Qw + (size_t)M_TOTAL*DD;
  f16* Vtw = Kw + (size_t)M_TOTAL*DD;   // 63 MB of workspace total

  proj_kernel<<<1024, 256, 0, stream>>>(x, y, Wq, bq, Wk, bk, Wv, bv, Qw, Kw, Vtw);
  flash_kernel<<<1024, 256, 0, stream>>>(Qw, Kw, Vtw, x, (float*)d_out);
}

// Round 5
// 325.643 us; speedup vs baseline: 3.7006x; 1.0923x over previous
//
#include <hip/hip_runtime.h>

#define LOG2E 1.44269504088896340736f

typedef _Float16 f16;
typedef __attribute__((ext_vector_type(4))) _Float16 f16x4;
typedef __attribute__((ext_vector_type(8))) _Float16 f16x8;
typedef __attribute__((ext_vector_type(4))) float f32x4;
typedef __attribute__((ext_vector_type(8))) unsigned short us8;

#define BB 32
#define SSX 2048
#define SSY 2048
#define DD 160
#define M_TOTAL (BB*SSX)   // 65536

#define PRS 168    // proj LDS row stride (f16)
#define VTRS 136   // proj V^T store buffer stride
#define RS 168     // flash K/Q LDS stride
#define P_RS 72    // flash P LDS stride (64 + 8)

__device__ __forceinline__ f32x4 mfma16(f16x8 a, f16x8 b, f32x4 c) {
  return __builtin_amdgcn_mfma_f32_16x16x32_f16(a, b, c, 0, 0, 0);
}

// ---- Projection: one projection per block (kind 0=Q,1=K,2=V), 128-row tiles.
// W-lo dropped (round-4: absmax unchanged by proj precision). No lambdas (round-3 spill lesson).
__global__ __launch_bounds__(256, 2) void proj_kernel(
    const float* __restrict__ x, const float* __restrict__ y,
    const float* __restrict__ Wq, const float* __restrict__ bq,
    const float* __restrict__ Wk, const float* __restrict__ bk,
    const float* __restrict__ Wv, const float* __restrict__ bv,
    f16* __restrict__ Qw, f16* __restrict__ Kw, f16* __restrict__ Vtw)
{
  __shared__ __align__(16) f16 buf[160*PRS];   // 53760 B
  const int t = threadIdx.x;
  const int wave = t >> 6;
  const int lane = t & 63;
  const int quad = lane >> 4;
  const int l16  = lane & 15;
  const int bid  = blockIdx.x;
  const int kind = bid % 3;          // 0=Q, 1=K, 2=V (K,V same tile adjacent -> L2 reuse of y)
  const int tile = bid / 3;
  const int row0 = tile * 128;
  const float* src  = (kind == 0) ? x  : y;
  const float* W    = (kind == 0) ? Wq : (kind == 1 ? Wk : Wv);
  const float* bias = (kind == 0) ? bq : (kind == 1 ? bk : bv);

  // stage 128x160 input tile fp32 -> f16
  for (int i = 0; i < 20; ++i) {
    int idx = t + i*256;
    int r = idx / 40, c4 = idx % 40;
    float4 v = *(const float4*)&src[(size_t)(row0 + r)*DD + c4*4];
    f16x4 h = { (f16)v.x, (f16)v.y, (f16)v.z, (f16)v.w };
    *(f16x4*)&buf[r*PRS + c4*4] = h;
  }
  __syncthreads();
  f16x8 afr0[5], afr1[5];
  #pragma unroll
  for (int ks = 0; ks < 5; ++ks) {
    afr0[ks] = *(const f16x8*)&buf[(wave*32 + l16)*PRS + ks*32 + quad*8];
    afr1[ks] = *(const f16x8*)&buf[(wave*32 + 16 + l16)*PRS + ks*32 + quad*8];
  }
  __syncthreads();

  // stage W 160x160 fp32 -> f16
  for (int i = 0; i < 25; ++i) {
    int idx = t + i*256;
    int r = idx / 40, c4 = idx % 40;
    float4 v = *(const float4*)&W[r*160 + c4*4];
    f16x4 h = { (f16)v.x, (f16)v.y, (f16)v.z, (f16)v.w };
    *(f16x4*)&buf[r*PRS + c4*4] = h;
  }
  __syncthreads();

  f32x4 acc0[10], acc1[10];
  #pragma unroll
  for (int nt = 0; nt < 10; ++nt) {
    float bs = bias[nt*16 + l16];
    acc0[nt] = (f32x4){bs,bs,bs,bs};
    acc1[nt] = (f32x4){bs,bs,bs,bs};
    #pragma unroll
    for (int ks = 0; ks < 5; ++ks) {
      f16x8 bfr = *(const f16x8*)&buf[(nt*16 + l16)*PRS + ks*32 + quad*8];
      acc0[nt] = mfma16(afr0[ks], bfr, acc0[nt]);
      acc1[nt] = mfma16(afr1[ks], bfr, acc1[nt]);
    }
  }
  __syncthreads();   // buf reads done before store-staging reuse

  if (kind < 2) {
    f16* dst = (kind == 0) ? Qw : Kw;
    #pragma unroll
    for (int nt = 0; nt < 10; ++nt)
      #pragma unroll
      for (int r = 0; r < 4; ++r) {
        buf[(wave*32 + quad*4 + r)*PRS + nt*16 + l16]      = (f16)acc0[nt][r];
        buf[(wave*32 + 16 + quad*4 + r)*PRS + nt*16 + l16] = (f16)acc1[nt][r];
      }
    __syncthreads();
    for (int i = 0; i < 10; ++i) {
      int idx = t + i*256;          // 2560 us8 = 128x160 f16
      int r = idx / 20, g = idx % 20;
      *(us8*)&dst[(size_t)(row0 + r)*DD + g*8] = *(const us8*)&buf[r*PRS + g*8];
    }
  } else {
    // V^T: acc -> buf[d][y_local] (stride VTRS) -> coalesced us8 stores
    #pragma unroll
    for (int nt = 0; nt < 10; ++nt)
      #pragma unroll
      for (int r = 0; r < 4; ++r) {
        buf[(nt*16 + l16)*VTRS + wave*32 + quad*4 + r]      = (f16)acc0[nt][r];
        buf[(nt*16 + l16)*VTRS + wave*32 + 16 + quad*4 + r] = (f16)acc1[nt][r];
      }
    __syncthreads();
    const int b  = row0 / SSY;
    const int y0 = row0 % SSY;
    for (int i = 0; i < 10; ++i) {
      int idx = t + i*256;          // 2560 us8 = 160 d x 128 y
      int d = idx / 16, yg = idx % 16;
      *(us8*)&Vtw[((size_t)b*DD + d)*SSY + y0 + yg*8] = *(const us8*)&buf[d*VTRS + yg*8];
    }
  }
}

// ---------------- Flash attention + residual: 128 q-rows/block, 32 q-rows/wave ----------------

#define LOAD_CHUNK(yb) { \
  const f16* ksrc = Kw + ((size_t)b*SSY + (yb))*DD; \
  const f16* vsrc = Vtw + (size_t)b*DD*SSY + (yb); \
  _Pragma("unroll") \
  for (int i = 0; i < 5; ++i) { \
    int idx = t + i*256; int r = idx/20, c = idx%20; \
    kreg[i] = *(const us8*)&ksrc[(size_t)r*DD + c*8]; \
  } \
  _Pragma("unroll") \
  for (int i = 0; i < 5; ++i) { \
    int idx = t + i*256; int d = idx>>3, g = idx&7; \
    vreg[i] = *(const us8*)&vsrc[(size_t)d*SSY + g*8]; \
  } \
}

#define STORE_CHUNK() { \
  _Pragma("unroll") \
  for (int i = 0; i < 5; ++i) { \
    int idx = t + i*256; int r = idx/20, c = idx%20; \
    *(us8*)&K_lds[r*RS + c*8] = kreg[i]; \
  } \
  _Pragma("unroll") \
  for (int i = 0; i < 5; ++i) { \
    int idx = t + i*256; int d = idx>>3, g = idx&7; \
    *(us8*)&Vt_lds[d*64 + ((g ^ (d & 7)) << 3)] = vreg[i]; \
  } \
}

__global__ __launch_bounds__(256, 2) void flash_kernel(
    const f16* __restrict__ Qw, const f16* __restrict__ Kw, const f16* __restrict__ Vtw,
    const float* __restrict__ x, float* __restrict__ out)
{
  __shared__ __align__(16) f16 K_lds[64*RS];      // 21504 B (also Q staging)
  __shared__ __align__(16) f16 Vt_lds[176*64];    // 22528 B (rows 160..175: ones column tile)
  __shared__ __align__(16) f16 P_lds[4*32*P_RS];  // 18432 B  -> total 62464 B, 2 blocks/CU
  const int t = threadIdx.x;
  const int wave = t >> 6;
  const int lane = t & 63;
  const int quad = lane >> 4;
  const int l16  = lane & 15;
  const int bid  = blockIdx.x;
  const int b    = bid >> 4;
  const int x0   = (bid & 15) * 128;

  // ones-tile init: row 160 = 1.0 (l-accumulator column), rows 161..175 = 0
  for (int idx = t; idx < 1024; idx += 256) {
    int d = idx >> 6, yy = idx & 63;
    Vt_lds[(160 + d)*64 + yy] = (d == 0) ? (f16)1.0f : (f16)0.0f;
  }

  // stage Q (128 rows in two 64-row passes through K_lds), hoist A-frags (32 rows/wave)
  f16x8 qfr0[5], qfr1[5];
  #pragma unroll
  for (int h = 0; h < 2; ++h) {
    if (h) __syncthreads();
    const f16* qsrc = Qw + ((size_t)b*SSX + x0 + h*64)*DD;
    for (int i = 0; i < 5; ++i) {
      int idx = t + i*256;
      int r = idx / 20, c = idx % 20;
      *(us8*)&K_lds[r*RS + c*8] = *(const us8*)&qsrc[(size_t)r*DD + c*8];
    }
    __syncthreads();
    if ((wave >> 1) == h) {
      const int base = (wave & 1)*32;
      #pragma unroll
      for (int ks = 0; ks < 5; ++ks) {
        qfr0[ks] = *(const f16x8*)&K_lds[(base + l16)*RS + ks*32 + quad*8];
        qfr1[ks] = *(const f16x8*)&K_lds[(base + 16 + l16)*RS + ks*32 + quad*8];
      }
    }
  }

  f32x4 acc0[11], acc1[11];   // tile 10 = l (ones column)
  #pragma unroll
  for (int i = 0; i < 11; ++i) { acc0[i] = (f32x4){0.f,0.f,0.f,0.f}; acc1[i] = (f32x4){0.f,0.f,0.f,0.f}; }
  float m0[4], m1[4];
  #pragma unroll
  for (int r = 0; r < 4; ++r) { m0[r] = -1e30f; m1[r] = -1e30f; }

  f16* Pw = &P_lds[wave*32*P_RS];
  us8 kreg[5], vreg[5];

  LOAD_CHUNK(0);
  for (int yc = 0; yc < SSY/64; ++yc) {
    __syncthreads();          // A: prev compute done reading LDS (drains in-flight prefetch)
    STORE_CHUNK();
    __syncthreads();          // B: LDS visible
    if (yc < SSY/64 - 1) LOAD_CHUNK((yc+1)*64);   // overlaps compute below

    // S = Q K^T  (two 16-row groups share each K fragment)
    f32x4 S0[4], S1[4];
    #pragma unroll
    for (int nt = 0; nt < 4; ++nt) { S0[nt] = (f32x4){0.f,0.f,0.f,0.f}; S1[nt] = (f32x4){0.f,0.f,0.f,0.f}; }
    #pragma unroll
    for (int nt = 0; nt < 4; ++nt)
      #pragma unroll
      for (int ks = 0; ks < 5; ++ks) {
        f16x8 kfr = *(const f16x8*)&K_lds[(nt*16 + l16)*RS + ks*32 + quad*8];
        S0[nt] = mfma16(qfr0[ks], kfr, S0[nt]);
        S1[nt] = mfma16(qfr1[ks], kfr, S1[nt]);
      }

    // online softmax (l handled by ones-column MFMA; only max tracked here)
    float n0[4], n1[4];
    bool changed = false;
    #pragma unroll
    for (int r = 0; r < 4; ++r) {
      float a = fmaxf(fmaxf(S0[0][r], S0[1][r]), fmaxf(S0[2][r], S0[3][r]));
      #pragma unroll
      for (int off = 1; off < 16; off <<= 1) a = fmaxf(a, __shfl_xor(a, off));
      n0[r] = fmaxf(m0[r], a);
      changed = changed || (n0[r] > m0[r]);
      float c = fmaxf(fmaxf(S1[0][r], S1[1][r]), fmaxf(S1[2][r], S1[3][r]));
      #pragma unroll
      for (int off = 1; off < 16; off <<= 1) c = fmaxf(c, __shfl_xor(c, off));
      n1[r] = fmaxf(m1[r], c);
      changed = changed || (n1[r] > m1[r]);
    }
    if (__any(changed)) {
      f32x4 av0, av1;
      #pragma unroll
      for (int r = 0; r < 4; ++r) {
        av0[r] = exp2f((m0[r] - n0[r])*LOG2E); m0[r] = n0[r];
        av1[r] = exp2f((m1[r] - n1[r])*LOG2E); m1[r] = n1[r];
      }
      #pragma unroll
      for (int i = 0; i < 11; ++i) { acc0[i] *= av0; acc1[i] *= av1; }
    }

    // P = exp(S - m) -> LDS (C/D layout -> A-operand layout round trip)
    #pragma unroll
    for (int r = 0; r < 4; ++r)
      #pragma unroll
      for (int nt = 0; nt < 4; ++nt) {
        Pw[(quad*4 + r)*P_RS + nt*16 + l16]      = (f16)exp2f((S0[nt][r] - m0[r])*LOG2E);
        Pw[(16 + quad*4 + r)*P_RS + nt*16 + l16] = (f16)exp2f((S1[nt][r] - m1[r])*LOG2E);
      }

    // acc += P V (tile 10 accumulates l via ones column); V fragments shared by both groups
    #pragma unroll
    for (int k2 = 0; k2 < 2; ++k2) {
      f16x8 p0 = *(const f16x8*)&Pw[l16*P_RS + k2*32 + quad*8];
      f16x8 p1 = *(const f16x8*)&Pw[(16 + l16)*P_RS + k2*32 + quad*8];
      #pragma unroll
      for (int dt = 0; dt < 11; ++dt) {
        f16x8 vfr = *(const f16x8*)&Vt_lds[(dt*16 + l16)*64 + (((k2*4 + quad) ^ (l16 & 7)) << 3)];
        acc0[dt] = mfma16(p0, vfr, acc0[dt]);
        acc1[dt] = mfma16(p1, vfr, acc1[dt]);
      }
    }
  }

  // epilogue: l = acc[10] col 0 (lanes quad*16), broadcast; out = acc/l + x
  float rl0[4], rl1[4];
  #pragma unroll
  for (int r = 0; r < 4; ++r) {
    rl0[r] = 1.f / __shfl(acc0[10][r], lane & 48);
    rl1[r] = 1.f / __shfl(acc1[10][r], lane & 48);
  }
  const size_t base = ((size_t)b*SSX + x0 + wave*32)*DD;
  #pragma unroll
  for (int dt = 0; dt < 10; ++dt)
    #pragma unroll
    for (int r = 0; r < 4; ++r) {
      size_t o0 = base + (size_t)(quad*4 + r)*DD + dt*16 + l16;
      size_t o1 = base + (size_t)(16 + quad*4 + r)*DD + dt*16 + l16;
      out[o0] = acc0[dt][r]*rl0[r] + x[o0];
      out[o1] = acc1[dt][r]*rl1[r] + x[o1];
    }
}

extern "C" void kernel_launch(void* const* d_in, const int* in_sizes, int n_in,
                              void* d_out, int out_size, void* d_ws, size_t ws_size,
                              hipStream_t stream) {
  const float* x  = (const float*)d_in[0];
  const float* y  = (const float*)d_in[1];
  const float* Wq = (const float*)d_in[2];
  const float* bq = (const float*)d_in[3];
  const float* Wk = (const float*)d_in[4];
  const float* bk = (const float*)d_in[5];
  const float* Wv = (const float*)d_in[6];
  const float* bv = (const float*)d_in[7];

  f16* Qw  = (f16*)d_ws;
  f16* Kw  = Qw + (size_t)M_TOTAL*DD;
  f16* Vtw = Kw + (size_t)M_TOTAL*DD;   // 63 MB of workspace total

  proj_kernel<<<1536, 256, 0, stream>>>(x, y, Wq, bq, Wk, bk, Wv, bv, Qw, Kw, Vtw);
  flash_kernel<<<512, 256, 0, stream>>>(Qw, Kw, Vtw, x, (float*)d_out);
}